// Round 1
// baseline (708.097 us; speedup 1.0000x reference)
//
#include <hip/hip_runtime.h>
#include <math.h>

#define N_TOK 2048
#define DM    1024
#define HD    2048
#define NE    8
#define RMAX  (N_TOK*2 + NE*64)   /* 4608 padded grouped rows */
#define TMAX  80                  /* max 64-row tiles: 64 + 8 */

// ---------------------------------------------------------------- gate
__global__ void gate_kernel(const float* __restrict__ inp,
                            const float* __restrict__ Wg,
                            const float* __restrict__ bg,
                            int* __restrict__ top_idx,
                            float* __restrict__ gate_w) {
  int wave = threadIdx.x >> 6;
  int lane = threadIdx.x & 63;
  int n = blockIdx.x * 4 + wave;
  if (n >= N_TOK) return;
  float acc[NE];
#pragma unroll
  for (int e = 0; e < NE; ++e) acc[e] = 0.f;
  const float4* wg4 = reinterpret_cast<const float4*>(Wg);
#pragma unroll
  for (int i = 0; i < DM / 64; ++i) {
    int d = i * 64 + lane;
    float x = inp[n * DM + d];
    float4 w0 = wg4[d * 2 + 0];
    float4 w1 = wg4[d * 2 + 1];
    acc[0] += x * w0.x; acc[1] += x * w0.y; acc[2] += x * w0.z; acc[3] += x * w0.w;
    acc[4] += x * w1.x; acc[5] += x * w1.y; acc[6] += x * w1.z; acc[7] += x * w1.w;
  }
#pragma unroll
  for (int off = 32; off > 0; off >>= 1) {
#pragma unroll
    for (int e = 0; e < NE; ++e) acc[e] += __shfl_xor(acc[e], off);
  }
  if (lane == 0) {
    float v0 = -1e30f, v1 = -1e30f; int i0 = -1, i1 = -1;
#pragma unroll
    for (int e = 0; e < NE; ++e) {
      float v = acc[e] + bg[e];
      if (v > v0)      { v1 = v0; i1 = i0; v0 = v; i0 = e; }
      else if (v > v1) { v1 = v;  i1 = e; }
    }
    float e1 = expf(v1 - v0);
    float s  = 1.f + e1;
    top_idx[n * 2]     = i0;
    top_idx[n * 2 + 1] = i1;
    gate_w[n * 2]      = 1.f / s;
    gate_w[n * 2 + 1]  = e1 / s;
  }
}

// ---------------------------------------------------------------- group
// Single block. Deterministic bucketing of (token,k) pairs by expert,
// padded to 64-row tiles. Emits tile table + inverse map for combine.
__global__ void group_kernel(const int* __restrict__ top_idx,
                             int* __restrict__ token_of,
                             int* __restrict__ inv_g,
                             int* __restrict__ tile_expert,
                             int* __restrict__ tile_row0,
                             int* __restrict__ n_tiles) {
  __shared__ int s_wtot[4];
  int tid = threadIdx.x, lane = tid & 63, wid = tid >> 6;
  int base = 0, tiles = 0;
  for (int e = 0; e < NE; ++e) {
    int cnt = 0;
    for (int c0 = 0; c0 < N_TOK; c0 += 256) {
      int n = c0 + tid;
      int t0 = top_idx[n * 2], t1 = top_idx[n * 2 + 1];
      bool f = (t0 == e) || (t1 == e);
      int k = (t0 == e) ? 0 : 1;
      unsigned long long m = __ballot(f);
      int lp = __popcll(m & ((1ull << lane) - 1ull));
      if (lane == 0) s_wtot[wid] = __popcll(m);
      __syncthreads();
      int wbase = 0;
      for (int w = 0; w < 4; ++w) if (w < wid) wbase += s_wtot[w];
      if (f) {
        int pos = base + cnt + wbase + lp;
        token_of[pos] = n;
        inv_g[n * 2 + k] = pos;
      }
      cnt += s_wtot[0] + s_wtot[1] + s_wtot[2] + s_wtot[3];
      __syncthreads();
    }
    int padded = (cnt + 63) & ~63;
    for (int i = cnt + tid; i < padded; i += 256) token_of[base + i] = -1;
    if (tid == 0) {
      for (int t = 0; t < padded / 64; ++t) {
        tile_expert[tiles + t] = e;
        tile_row0[tiles + t]   = base + t * 64;
      }
    }
    tiles += padded / 64;
    base  += padded;
    __syncthreads();
  }
  if (tid == 0) n_tiles[0] = tiles;
}

// ---------------------------------------------------------------- ffn1
// H = gelu(X @ W1[e] + b1[e]); X gathered from inp via token_of.
__global__ __launch_bounds__(256) void ffn1_kernel(
    const float* __restrict__ inp, const float* __restrict__ W1,
    const float* __restrict__ b1,
    const int* __restrict__ token_of, const int* __restrict__ tile_expert,
    const int* __restrict__ tile_row0, const int* __restrict__ n_tiles,
    float* __restrict__ Hbuf) {
  int t = blockIdx.x;
  if (t >= n_tiles[0]) return;
  int e    = tile_expert[t];
  int row0 = tile_row0[t];
  int h0   = blockIdx.y * 64;
  __shared__ float As[64][17];
  __shared__ float Bs[16][64];
  int tid = threadIdx.x;
  int tx = tid & 15, ty = tid >> 4;
  float acc[4][4] = {};
  int tok[4];
#pragma unroll
  for (int p = 0; p < 4; ++p) {
    int idx = tid + p * 256;
    tok[p] = token_of[row0 + (idx >> 4)];
  }
  const float* W1e = W1 + (size_t)e * DM * HD;
  for (int kc = 0; kc < DM; kc += 16) {
#pragma unroll
    for (int p = 0; p < 4; ++p) {
      int idx = tid + p * 256;
      int r = idx >> 4, kk = idx & 15;
      As[r][kk] = (tok[p] < 0) ? 0.f : inp[(size_t)tok[p] * DM + kc + kk];
    }
#pragma unroll
    for (int p = 0; p < 4; ++p) {
      int idx = tid + p * 256;
      int kk = idx >> 6, c = idx & 63;
      Bs[kk][c] = W1e[(size_t)(kc + kk) * HD + h0 + c];
    }
    __syncthreads();
#pragma unroll
    for (int kk = 0; kk < 16; ++kk) {
      float a[4], b[4];
#pragma unroll
      for (int i = 0; i < 4; ++i) a[i] = As[ty * 4 + i][kk];
#pragma unroll
      for (int j = 0; j < 4; ++j) b[j] = Bs[kk][tx * 4 + j];
#pragma unroll
      for (int i = 0; i < 4; ++i)
#pragma unroll
        for (int j = 0; j < 4; ++j) acc[i][j] += a[i] * b[j];
    }
    __syncthreads();
  }
#pragma unroll
  for (int i = 0; i < 4; ++i) {
    int r = row0 + ty * 4 + i;
#pragma unroll
    for (int j = 0; j < 4; ++j) {
      int h = h0 + tx * 4 + j;
      float x = acc[i][j] + b1[e * HD + h];
      float g = 0.5f * x * (1.f + tanhf(0.7978845608f * (x + 0.044715f * x * x * x)));
      Hbuf[(size_t)r * HD + h] = g;
    }
  }
}

// ---------------------------------------------------------------- ffn2
// Y = H @ W2[e] + b2[e]
__global__ __launch_bounds__(256) void ffn2_kernel(
    const float* __restrict__ Hbuf, const float* __restrict__ W2,
    const float* __restrict__ b2,
    const int* __restrict__ tile_expert, const int* __restrict__ tile_row0,
    const int* __restrict__ n_tiles,
    float* __restrict__ Ybuf) {
  int t = blockIdx.x;
  if (t >= n_tiles[0]) return;
  int e    = tile_expert[t];
  int row0 = tile_row0[t];
  int d0   = blockIdx.y * 64;
  __shared__ float As[64][17];
  __shared__ float Bs[16][64];
  int tid = threadIdx.x;
  int tx = tid & 15, ty = tid >> 4;
  float acc[4][4] = {};
  const float* W2e = W2 + (size_t)e * HD * DM;
  for (int kc = 0; kc < HD; kc += 16) {
#pragma unroll
    for (int p = 0; p < 4; ++p) {
      int idx = tid + p * 256;
      int r = idx >> 4, kk = idx & 15;
      As[r][kk] = Hbuf[(size_t)(row0 + r) * HD + kc + kk];
    }
#pragma unroll
    for (int p = 0; p < 4; ++p) {
      int idx = tid + p * 256;
      int kk = idx >> 6, c = idx & 63;
      Bs[kk][c] = W2e[(size_t)(kc + kk) * DM + d0 + c];
    }
    __syncthreads();
#pragma unroll
    for (int kk = 0; kk < 16; ++kk) {
      float a[4], b[4];
#pragma unroll
      for (int i = 0; i < 4; ++i) a[i] = As[ty * 4 + i][kk];
#pragma unroll
      for (int j = 0; j < 4; ++j) b[j] = Bs[kk][tx * 4 + j];
#pragma unroll
      for (int i = 0; i < 4; ++i)
#pragma unroll
        for (int j = 0; j < 4; ++j) acc[i][j] += a[i] * b[j];
    }
    __syncthreads();
  }
#pragma unroll
  for (int i = 0; i < 4; ++i) {
    int r = row0 + ty * 4 + i;
#pragma unroll
    for (int j = 0; j < 4; ++j) {
      int d = d0 + tx * 4 + j;
      Ybuf[(size_t)r * DM + d] = acc[i][j] + b2[e * DM + d];
    }
  }
}

// ---------------------------------------------------------------- combine
__global__ void combine_kernel(const float* __restrict__ Ybuf,
                               const int* __restrict__ inv_g,
                               const float* __restrict__ gate_w,
                               float* __restrict__ out) {
  int n = blockIdx.x;
  int r0 = inv_g[n * 2], r1 = inv_g[n * 2 + 1];
  float g0 = gate_w[n * 2], g1 = gate_w[n * 2 + 1];
  const float4* y0 = reinterpret_cast<const float4*>(Ybuf + (size_t)r0 * DM);
  const float4* y1 = reinterpret_cast<const float4*>(Ybuf + (size_t)r1 * DM);
  float4* o = reinterpret_cast<float4*>(out + (size_t)n * DM);
  int i = threadIdx.x;   // 256 threads * float4 = 1024 floats
  float4 a = y0[i], b = y1[i];
  float4 rv;
  rv.x = g0 * a.x + g1 * b.x;
  rv.y = g0 * a.y + g1 * b.y;
  rv.z = g0 * a.z + g1 * b.z;
  rv.w = g0 * a.w + g1 * b.w;
  o[i] = rv;
}

// ---------------------------------------------------------------- launch
extern "C" void kernel_launch(void* const* d_in, const int* in_sizes, int n_in,
                              void* d_out, int out_size, void* d_ws, size_t ws_size,
                              hipStream_t stream) {
  const float* inp = (const float*)d_in[0];
  const float* Wg  = (const float*)d_in[1];
  const float* bg  = (const float*)d_in[2];
  const float* W1  = (const float*)d_in[3];
  const float* b1  = (const float*)d_in[4];
  const float* W2  = (const float*)d_in[5];
  const float* b2  = (const float*)d_in[6];
  float* out = (float*)d_out;

  char* ws = (char*)d_ws;
  size_t off = 0;
  auto alloc = [&](size_t bytes) {
    size_t o = off;
    off = (off + bytes + 255) & ~(size_t)255;
    return o;
  };
  int*   top_idx     = (int*)  (ws + alloc(N_TOK * 2 * sizeof(int)));
  float* gate_w      = (float*)(ws + alloc(N_TOK * 2 * sizeof(float)));
  int*   token_of    = (int*)  (ws + alloc(RMAX * sizeof(int)));
  int*   inv_g       = (int*)  (ws + alloc(N_TOK * 2 * sizeof(int)));
  int*   tile_expert = (int*)  (ws + alloc(TMAX * sizeof(int)));
  int*   tile_row0   = (int*)  (ws + alloc(TMAX * sizeof(int)));
  int*   n_tiles     = (int*)  (ws + alloc(sizeof(int)));
  float* Hbuf        = (float*)(ws + alloc((size_t)RMAX * HD * sizeof(float)));
  float* Ybuf        = (float*)(ws + alloc((size_t)RMAX * DM * sizeof(float)));
  (void)ws_size;

  gate_kernel<<<N_TOK / 4, 256, 0, stream>>>(inp, Wg, bg, top_idx, gate_w);
  group_kernel<<<1, 256, 0, stream>>>(top_idx, token_of, inv_g,
                                      tile_expert, tile_row0, n_tiles);
  dim3 g1(TMAX, HD / 64);
  ffn1_kernel<<<g1, 256, 0, stream>>>(inp, W1, b1, token_of, tile_expert,
                                      tile_row0, n_tiles, Hbuf);
  dim3 g2(TMAX, DM / 64);
  ffn2_kernel<<<g2, 256, 0, stream>>>(Hbuf, W2, b2, tile_expert, tile_row0,
                                      n_tiles, Ybuf);
  combine_kernel<<<N_TOK, 256, 0, stream>>>(Ybuf, inv_g, gate_w, out);
}

// Round 2
// 159.891 us; speedup vs baseline: 4.4286x; 4.4286x over previous
//
#include <hip/hip_runtime.h>
#include <math.h>

#define N_TOK 2048
#define DM    1024
#define HD    2048
#define NE    8
#define RMAX  5120                /* 4096 + 8*128 pad */
#define TMAX  40                  /* max 128-row tiles */

typedef short short8 __attribute__((ext_vector_type(8)));
typedef float f32x4  __attribute__((ext_vector_type(4)));

__device__ inline unsigned short f2b(float f) {   // fp32 -> bf16 RNE
  unsigned int u = __float_as_uint(f);
  return (unsigned short)((u + 0x7FFFu + ((u >> 16) & 1u)) >> 16);
}
__device__ inline float b2f(unsigned short s) {
  return __uint_as_float(((unsigned int)s) << 16);
}
__device__ inline void gload_lds16(const void* g, void* l) {
  __builtin_amdgcn_global_load_lds(
      (const __attribute__((address_space(1))) unsigned int*)g,
      (__attribute__((address_space(3))) unsigned int*)l, 16, 0, 0);
}

// ---------------------------------------------------------------- gate
__global__ void gate_kernel(const float* __restrict__ inp,
                            const float* __restrict__ Wg,
                            const float* __restrict__ bg,
                            int* __restrict__ top_idx,
                            float* __restrict__ gate_w) {
  int wave = threadIdx.x >> 6;
  int lane = threadIdx.x & 63;
  int n = blockIdx.x * 4 + wave;
  if (n >= N_TOK) return;
  float acc[NE];
#pragma unroll
  for (int e = 0; e < NE; ++e) acc[e] = 0.f;
  const float4* wg4 = reinterpret_cast<const float4*>(Wg);
#pragma unroll
  for (int i = 0; i < DM / 64; ++i) {
    int d = i * 64 + lane;
    float x = inp[n * DM + d];
    float4 w0 = wg4[d * 2 + 0];
    float4 w1 = wg4[d * 2 + 1];
    acc[0] += x * w0.x; acc[1] += x * w0.y; acc[2] += x * w0.z; acc[3] += x * w0.w;
    acc[4] += x * w1.x; acc[5] += x * w1.y; acc[6] += x * w1.z; acc[7] += x * w1.w;
  }
#pragma unroll
  for (int off = 32; off > 0; off >>= 1) {
#pragma unroll
    for (int e = 0; e < NE; ++e) acc[e] += __shfl_xor(acc[e], off);
  }
  if (lane == 0) {
    float v0 = -1e30f, v1 = -1e30f; int i0 = -1, i1 = -1;
#pragma unroll
    for (int e = 0; e < NE; ++e) {
      float v = acc[e] + bg[e];
      if (v > v0)      { v1 = v0; i1 = i0; v0 = v; i0 = e; }
      else if (v > v1) { v1 = v;  i1 = e; }
    }
    float e1 = expf(v1 - v0);
    float s  = 1.f + e1;
    top_idx[n * 2]     = i0;
    top_idx[n * 2 + 1] = i1;
    gate_w[n * 2]      = 1.f / s;
    gate_w[n * 2 + 1]  = e1 / s;
  }
}

// ---------------------------------------------------------------- group
// Single block. Deterministic bucketing of (token,k) pairs by expert,
// padded to 128-row tiles.
__global__ void group_kernel(const int* __restrict__ top_idx,
                             int* __restrict__ token_of,
                             int* __restrict__ inv_g,
                             int* __restrict__ tile_expert,
                             int* __restrict__ tile_row0,
                             int* __restrict__ n_tiles) {
  __shared__ int s_wtot[4];
  int tid = threadIdx.x, lane = tid & 63, wid = tid >> 6;
  int base = 0, tiles = 0;
  for (int e = 0; e < NE; ++e) {
    int cnt = 0;
    for (int c0 = 0; c0 < N_TOK; c0 += 256) {
      int n = c0 + tid;
      int t0 = top_idx[n * 2], t1 = top_idx[n * 2 + 1];
      bool f = (t0 == e) || (t1 == e);
      int k = (t0 == e) ? 0 : 1;
      unsigned long long m = __ballot(f);
      int lp = __popcll(m & ((1ull << lane) - 1ull));
      if (lane == 0) s_wtot[wid] = __popcll(m);
      __syncthreads();
      int wbase = 0;
      for (int w = 0; w < 4; ++w) if (w < wid) wbase += s_wtot[w];
      if (f) {
        int pos = base + cnt + wbase + lp;
        token_of[pos] = n;
        inv_g[n * 2 + k] = pos;
      }
      cnt += s_wtot[0] + s_wtot[1] + s_wtot[2] + s_wtot[3];
      __syncthreads();
    }
    int padded = (cnt + 127) & ~127;
    for (int i = cnt + tid; i < padded; i += 256) token_of[base + i] = -1;
    if (tid == 0) {
      for (int t = 0; t < padded / 128; ++t) {
        tile_expert[tiles + t] = e;
        tile_row0[tiles + t]   = base + t * 128;
      }
    }
    tiles += padded / 128;
    base  += padded;
    __syncthreads();
  }
  if (tid == 0) n_tiles[0] = tiles;
}

// ---------------------------------------------------------------- xcvt
// inp fp32 [N][D] -> Xb bf16
__global__ void xcvt_kernel(const float* __restrict__ inp,
                            unsigned short* __restrict__ Xb) {
  int i = (blockIdx.x * 256 + threadIdx.x) * 8;
  float4 a = *(const float4*)(inp + i);
  float4 b = *(const float4*)(inp + i + 4);
  ushort4 pa, pb;
  pa.x = f2b(a.x); pa.y = f2b(a.y); pa.z = f2b(a.z); pa.w = f2b(a.w);
  pb.x = f2b(b.x); pb.y = f2b(b.y); pb.z = f2b(b.z); pb.w = f2b(b.w);
  *(ushort4*)(Xb + i)     = pa;
  *(ushort4*)(Xb + i + 4) = pb;
}

// ---------------------------------------------------------------- wcvt
// z<NE : W1[e] [DM][HD] fp32 -> W1T[e] [HD][DM] bf16
// z>=NE: W2[e] [HD][DM] fp32 -> W2T[e] [DM][HD] bf16
__global__ void wcvt_kernel(const float* __restrict__ W1,
                            const float* __restrict__ W2,
                            unsigned short* __restrict__ W1T,
                            unsigned short* __restrict__ W2T) {
  int z = blockIdx.z;
  const float* src; unsigned short* dst; int R, C;
  if (z < NE) { src = W1 + (size_t)z * DM * HD; dst = W1T + (size_t)z * DM * HD; R = DM; C = HD; }
  else        { src = W2 + (size_t)(z - NE) * HD * DM; dst = W2T + (size_t)(z - NE) * HD * DM; R = HD; C = DM; }
  int c0 = blockIdx.x * 64, r0 = blockIdx.y * 64;
  if (c0 >= C || r0 >= R) return;
  __shared__ float t[64][65];
  int tid = threadIdx.x;
#pragma unroll
  for (int p = 0; p < 16; ++p) {
    int idx = tid + p * 256;
    int r = idx >> 6, c = idx & 63;
    t[r][c] = src[(size_t)(r0 + r) * C + c0 + c];
  }
  __syncthreads();
#pragma unroll
  for (int p = 0; p < 16; ++p) {
    int idx = tid + p * 256;
    int c = idx >> 6, r = idx & 63;
    dst[(size_t)(c0 + c) * R + r0 + r] = f2b(t[r][c]);
  }
}

// ---------------------------------------------------------------- ffn1
// H[row][h] = gelu( X[tok(row)] . W1T[h] + b1 ), 128x128 tile, MFMA bf16
__global__ __launch_bounds__(256) void ffn1_mfma(
    const unsigned short* __restrict__ Xb,
    const unsigned short* __restrict__ W1T,
    const float* __restrict__ b1,
    const unsigned short* __restrict__ zbuf,
    const int* __restrict__ token_of, const int* __restrict__ tile_expert,
    const int* __restrict__ tile_row0, const int* __restrict__ n_tiles,
    unsigned short* __restrict__ Hbuf) {
  if ((int)blockIdx.x >= n_tiles[0]) return;
  int e    = tile_expert[blockIdx.x];
  int row0 = tile_row0[blockIdx.x];
  int h0   = blockIdx.y * 128;
  __shared__ __align__(16) unsigned short Asl[128][32];
  __shared__ __align__(16) unsigned short Bsl[128][32];
  int tid = threadIdx.x, lane = tid & 63;
  int wid = tid >> 6, wr = wid >> 1, wc = wid & 1;
  int l15 = lane & 15, l4 = lane >> 4;

  int tk[2];
#pragma unroll
  for (int q = 0; q < 2; ++q) tk[q] = token_of[row0 + ((tid + q * 256) >> 2)];

  f32x4 acc[4][4] = {};
  const unsigned short* W1e = W1T + (size_t)e * HD * DM;   // [HD][DM]

  for (int kc = 0; kc < DM; kc += 32) {
    __syncthreads();
#pragma unroll
    for (int q = 0; q < 2; ++q) {
      int idx = tid + q * 256;
      const unsigned short* ga = (tk[q] < 0)
          ? zbuf
          : Xb + (size_t)tk[q] * DM + kc + (idx & 3) * 8;
      gload_lds16(ga, (char*)&Asl[0][0] + (size_t)idx * 16);
      const unsigned short* gb =
          W1e + (size_t)(h0 + (idx >> 2)) * DM + kc + (idx & 3) * 8;
      gload_lds16(gb, (char*)&Bsl[0][0] + (size_t)idx * 16);
    }
    __syncthreads();
    short8 a[4], b[4];
#pragma unroll
    for (int m = 0; m < 4; ++m)
      a[m] = *(const short8*)&Asl[wr * 64 + m * 16 + l15][l4 * 8];
#pragma unroll
    for (int n = 0; n < 4; ++n)
      b[n] = *(const short8*)&Bsl[wc * 64 + n * 16 + l15][l4 * 8];
#pragma unroll
    for (int m = 0; m < 4; ++m)
#pragma unroll
      for (int n = 0; n < 4; ++n)
        acc[m][n] = __builtin_amdgcn_mfma_f32_16x16x32_bf16(a[m], b[n], acc[m][n], 0, 0, 0);
  }

  float bias[4];
#pragma unroll
  for (int n = 0; n < 4; ++n) bias[n] = b1[e * HD + h0 + wc * 64 + n * 16 + l15];
#pragma unroll
  for (int m = 0; m < 4; ++m) {
#pragma unroll
    for (int n = 0; n < 4; ++n) {
      int col = h0 + wc * 64 + n * 16 + l15;
#pragma unroll
      for (int j = 0; j < 4; ++j) {
        int row = row0 + wr * 64 + m * 16 + l4 * 4 + j;
        float x = acc[m][n][j] + bias[n];
        float g = 0.5f * x * (1.f + tanhf(0.7978845608f * (x + 0.044715f * x * x * x)));
        Hbuf[(size_t)row * HD + col] = f2b(g);
      }
    }
  }
}

// ---------------------------------------------------------------- ffn2
// Y[row][d] = H[row] . W2T[d] + b2, 128x128 tile, MFMA bf16
__global__ __launch_bounds__(256) void ffn2_mfma(
    const unsigned short* __restrict__ Hbuf,
    const unsigned short* __restrict__ W2T,
    const float* __restrict__ b2,
    const int* __restrict__ tile_expert, const int* __restrict__ tile_row0,
    const int* __restrict__ n_tiles,
    unsigned short* __restrict__ Ybuf) {
  if ((int)blockIdx.x >= n_tiles[0]) return;
  int e    = tile_expert[blockIdx.x];
  int row0 = tile_row0[blockIdx.x];
  int d0   = blockIdx.y * 128;
  __shared__ __align__(16) unsigned short Asl[128][32];
  __shared__ __align__(16) unsigned short Bsl[128][32];
  int tid = threadIdx.x, lane = tid & 63;
  int wid = tid >> 6, wr = wid >> 1, wc = wid & 1;
  int l15 = lane & 15, l4 = lane >> 4;

  f32x4 acc[4][4] = {};
  const unsigned short* W2e = W2T + (size_t)e * DM * HD;   // [DM][HD]

  for (int kc = 0; kc < HD; kc += 32) {
    __syncthreads();
#pragma unroll
    for (int q = 0; q < 2; ++q) {
      int idx = tid + q * 256;
      const unsigned short* ga =
          Hbuf + (size_t)(row0 + (idx >> 2)) * HD + kc + (idx & 3) * 8;
      gload_lds16(ga, (char*)&Asl[0][0] + (size_t)idx * 16);
      const unsigned short* gb =
          W2e + (size_t)(d0 + (idx >> 2)) * HD + kc + (idx & 3) * 8;
      gload_lds16(gb, (char*)&Bsl[0][0] + (size_t)idx * 16);
    }
    __syncthreads();
    short8 a[4], b[4];
#pragma unroll
    for (int m = 0; m < 4; ++m)
      a[m] = *(const short8*)&Asl[wr * 64 + m * 16 + l15][l4 * 8];
#pragma unroll
    for (int n = 0; n < 4; ++n)
      b[n] = *(const short8*)&Bsl[wc * 64 + n * 16 + l15][l4 * 8];
#pragma unroll
    for (int m = 0; m < 4; ++m)
#pragma unroll
      for (int n = 0; n < 4; ++n)
        acc[m][n] = __builtin_amdgcn_mfma_f32_16x16x32_bf16(a[m], b[n], acc[m][n], 0, 0, 0);
  }

  float bias[4];
#pragma unroll
  for (int n = 0; n < 4; ++n) bias[n] = b2[e * DM + d0 + wc * 64 + n * 16 + l15];
#pragma unroll
  for (int m = 0; m < 4; ++m) {
#pragma unroll
    for (int n = 0; n < 4; ++n) {
      int col = d0 + wc * 64 + n * 16 + l15;
#pragma unroll
      for (int j = 0; j < 4; ++j) {
        int row = row0 + wr * 64 + m * 16 + l4 * 4 + j;
        Ybuf[(size_t)row * DM + col] = f2b(acc[m][n][j] + bias[n]);
      }
    }
  }
}

// ---------------------------------------------------------------- combine
__global__ void combine_kernel(const unsigned short* __restrict__ Ybuf,
                               const int* __restrict__ inv_g,
                               const float* __restrict__ gate_w,
                               float* __restrict__ out) {
  int n = blockIdx.x;
  int r0 = inv_g[n * 2], r1 = inv_g[n * 2 + 1];
  float g0 = gate_w[n * 2], g1 = gate_w[n * 2 + 1];
  int i = threadIdx.x;          // 256 threads * 4 elems = 1024
  ushort4 a = *(const ushort4*)(Ybuf + (size_t)r0 * DM + i * 4);
  ushort4 b = *(const ushort4*)(Ybuf + (size_t)r1 * DM + i * 4);
  float4 rv;
  rv.x = g0 * b2f(a.x) + g1 * b2f(b.x);
  rv.y = g0 * b2f(a.y) + g1 * b2f(b.y);
  rv.z = g0 * b2f(a.z) + g1 * b2f(b.z);
  rv.w = g0 * b2f(a.w) + g1 * b2f(b.w);
  *(float4*)(out + (size_t)n * DM + i * 4) = rv;
}

// ---------------------------------------------------------------- launch
extern "C" void kernel_launch(void* const* d_in, const int* in_sizes, int n_in,
                              void* d_out, int out_size, void* d_ws, size_t ws_size,
                              hipStream_t stream) {
  const float* inp = (const float*)d_in[0];
  const float* Wg  = (const float*)d_in[1];
  const float* bg  = (const float*)d_in[2];
  const float* W1  = (const float*)d_in[3];
  const float* b1  = (const float*)d_in[4];
  const float* W2  = (const float*)d_in[5];
  const float* b2  = (const float*)d_in[6];
  float* out = (float*)d_out;

  char* ws = (char*)d_ws;
  size_t off = 0;
  auto alloc = [&](size_t bytes) {
    size_t o = off;
    off = (off + bytes + 255) & ~(size_t)255;
    return o;
  };
  int*   top_idx     = (int*)  (ws + alloc(N_TOK * 2 * sizeof(int)));
  float* gate_w      = (float*)(ws + alloc(N_TOK * 2 * sizeof(float)));
  int*   token_of    = (int*)  (ws + alloc(RMAX * sizeof(int)));
  int*   inv_g       = (int*)  (ws + alloc(N_TOK * 2 * sizeof(int)));
  int*   tile_expert = (int*)  (ws + alloc(TMAX * sizeof(int)));
  int*   tile_row0   = (int*)  (ws + alloc(TMAX * sizeof(int)));
  int*   n_tiles     = (int*)  (ws + alloc(sizeof(int)));
  unsigned short* zbuf = (unsigned short*)(ws + alloc(256));
  unsigned short* Xb   = (unsigned short*)(ws + alloc((size_t)N_TOK * DM * 2));
  unsigned short* W1T  = (unsigned short*)(ws + alloc((size_t)NE * DM * HD * 2));
  unsigned short* W2T  = (unsigned short*)(ws + alloc((size_t)NE * DM * HD * 2));
  unsigned short* Hbuf = (unsigned short*)(ws + alloc((size_t)RMAX * HD * 2));
  unsigned short* Ybuf = (unsigned short*)(ws + alloc((size_t)RMAX * DM * 2));
  (void)ws_size;

  hipMemsetAsync(zbuf, 0, 256, stream);
  gate_kernel<<<N_TOK / 4, 256, 0, stream>>>(inp, Wg, bg, top_idx, gate_w);
  group_kernel<<<1, 256, 0, stream>>>(top_idx, token_of, inv_g,
                                      tile_expert, tile_row0, n_tiles);
  xcvt_kernel<<<(N_TOK * DM) / (256 * 8), 256, 0, stream>>>(inp, Xb);
  wcvt_kernel<<<dim3(32, 32, 2 * NE), 256, 0, stream>>>(W1, W2, W1T, W2T);
  ffn1_mfma<<<dim3(TMAX, HD / 128), 256, 0, stream>>>(
      Xb, W1T, b1, zbuf, token_of, tile_expert, tile_row0, n_tiles, Hbuf);
  ffn2_mfma<<<dim3(TMAX, DM / 128), 256, 0, stream>>>(
      Hbuf, W2T, b2, tile_expert, tile_row0, n_tiles, Ybuf);
  combine_kernel<<<N_TOK, 256, 0, stream>>>(Ybuf, inv_g, gate_w, out);
}